// Round 15
// baseline (632.445 us; speedup 1.0000x reference)
//
#include <hip/hip_runtime.h>
#include <hip/hip_bf16.h>
#include <math.h>

#define B_  16
#define T_  1024
#define D_  768
#define S_  64
#define H_  8
#define DH_ 96
#define FF_ 3072
#define TD_ 512
#define V_  49408
#define M_  1024  // B_*S_
#define ZSL 32
#define SCH 32    // seg_partial frames per chunk

typedef __bf16 bf16_8 __attribute__((ext_vector_type(8)));
typedef __bf16 bf16x4 __attribute__((ext_vector_type(4)));
typedef float f32x4 __attribute__((ext_vector_type(4)));

__device__ __forceinline__ void async16(const void* g, void* lds) {
  __builtin_amdgcn_global_load_lds((const __attribute__((address_space(1))) void*)g,
                                   (__attribute__((address_space(3))) void*)lds,
                                   16, 0, 0);
}

__device__ __forceinline__ float blk_sum256(float v, float* red) {
#pragma unroll
  for (int o = 32; o > 0; o >>= 1) v += __shfl_down(v, o, 64);
  const int w = threadIdx.x >> 6;
  if ((threadIdx.x & 63) == 0) red[w] = v;
  __syncthreads();
  float t = red[0] + red[1] + red[2] + red[3];
  __syncthreads();
  return t;
}

// ---------------- GEMM 128x128: C[M,N] = A[M,K](bf16) * B[N,K]^T(bf16) ------------
// MODE 0: fp32 out (+bias)  1: relu bf16 out (+bias)
// MODE 6: fp32 atomicAdd into shared output (split-K; bias handled by consumer;
//         for PV the output is a 2 MB L2-resident accumulator -> no HBM slices)
// SWZ=2: grid (1024,1,1); XCD x owns z in {4x..4x+3} entirely (8 mb x 4 nb each).
// 2-phase double-buffered pipeline (proven). launch_bounds(256,4): 4 blocks/CU.
// Split-K z tuned to z in {2,4}: z=8 measured overhead-dominated (R13).
template <int MODE, int SWZ>
__global__ __launch_bounds__(256, 4) void gemm_nt(
    const __bf16* __restrict__ A, const __bf16* __restrict__ Bm,
    const float* __restrict__ bias, void* __restrict__ Cv,
    int Nr, int Kr, int kIterPerZ) {
  __shared__ __bf16 Als[2][128 * 32];
  __shared__ __bf16 Bls[2][128 * 32];
  const int tid = threadIdx.x;
  const int w = tid >> 6, l = tid & 63;
  int mb, nb, zb;
  if (SWZ == 2) {
    const int f = blockIdx.x;          // [0,1024)
    const int x = f & 7, o = f >> 3;   // XCD x owns z = 4x + (o>>5)
    zb = 4 * x + (o >> 5);
    const int r = o & 31;
    mb = r >> 2;                       // 0..7 (A-tile reused across 4 nb)
    nb = r & 3;                        // 0..3
  } else {
    mb = blockIdx.x; nb = blockIdx.y; zb = blockIdx.z;
  }
  const int m0 = mb * 128, n0 = nb * 128;
  const int totIt = Kr >> 5;
  const int it0 = zb * kIterPerZ;
  const int nIt = min(kIterPerZ, totIt - it0);
  if (nIt <= 0) return;

  const int i0 = w * 128 + l, i1 = i0 + 64;
  const int ra0 = i0 >> 2, ca0 = ((i0 & 3) ^ ((i0 >> 3) & 3)) * 8;
  const int ra1 = i1 >> 2, ca1 = ((i1 & 3) ^ ((i1 >> 3) & 3)) * 8;
  const __bf16* gA0 = A + (size_t)(m0 + ra0) * Kr + ca0;
  const __bf16* gA1 = A + (size_t)(m0 + ra1) * Kr + ca1;
  const __bf16* gB0 = Bm + (size_t)(n0 + ra0) * Kr + ca0;
  const __bf16* gB1 = Bm + (size_t)(n0 + ra1) * Kr + ca1;
  const int o0 = (w * 128 + 0) * 8;
  const int o1 = (w * 128 + 64) * 8;

  const int wm = (w & 1) * 64, wn = (w >> 1) * 64;
  const int frow = l & 15, fq = l >> 4;
  const int fc = (fq ^ ((frow >> 1) & 3)) * 8;

  f32x4 acc[4][4];
  const f32x4 zero = {0.f, 0.f, 0.f, 0.f};
#pragma unroll
  for (int a = 0; a < 4; ++a)
#pragma unroll
    for (int b = 0; b < 4; ++b) acc[a][b] = zero;

  auto stage = [&](int buf, int it) {
    const size_t k0 = (size_t)(it0 + it) << 5;
    async16(gA0 + k0, &Als[buf][o0]);
    async16(gA1 + k0, &Als[buf][o1]);
    async16(gB0 + k0, &Bls[buf][o0]);
    async16(gB1 + k0, &Bls[buf][o1]);
  };

  stage(0, 0);
  asm volatile("s_waitcnt vmcnt(0)" ::: "memory");
  __builtin_amdgcn_s_barrier();

  for (int it = 0; it < nIt; ++it) {
    const int cur = it & 1;
    if (it + 1 < nIt) stage(cur ^ 1, it + 1);
    bf16_8 af[4], bf[4];
#pragma unroll
    for (int mi = 0; mi < 4; ++mi)
      af[mi] = *(const bf16_8*)&Als[cur][(wm + mi * 16 + frow) * 32 + fc];
#pragma unroll
    for (int ni = 0; ni < 4; ++ni)
      bf[ni] = *(const bf16_8*)&Bls[cur][(wn + ni * 16 + frow) * 32 + fc];
#pragma unroll
    for (int mi = 0; mi < 4; ++mi)
#pragma unroll
      for (int ni = 0; ni < 4; ++ni)
        acc[mi][ni] = __builtin_amdgcn_mfma_f32_16x16x32_bf16(af[mi], bf[ni], acc[mi][ni], 0, 0, 0);
    asm volatile("s_waitcnt vmcnt(0) lgkmcnt(0)" ::: "memory");
    __builtin_amdgcn_s_barrier();
  }

  float* Cs = (float*)Cv;
#pragma unroll
  for (int mi = 0; mi < 4; ++mi) {
#pragma unroll
    for (int r = 0; r < 4; ++r) {
      const int row = m0 + wm + mi * 16 + fq * 4 + r;
#pragma unroll
      for (int ni = 0; ni < 4; ++ni) {
        const int col = n0 + wn + ni * 16 + frow;
        float v = acc[mi][ni][r];
        if (MODE == 0) {
          if (bias) v += bias[col];
          Cs[(size_t)row * Nr + col] = v;
        } else if (MODE == 1) {
          v += bias[col];
          ((__bf16*)Cv)[(size_t)row * Nr + col] = (__bf16)fmaxf(v, 0.f);
        } else {
          atomicAdd(&Cs[(size_t)row * Nr + col], v);
        }
      }
    }
  }
}

// ---------------- GEMM 256x128 (GEMM1): exp epilogue + fused rowsum ---------------
// grid: 1-D, 4*nTiles blocks, XCD-swizzled. 2-phase pipeline. Proven: 113.7 us.
__global__ __launch_bounds__(256, 2) void gemm_big_exp(
    const __bf16* __restrict__ A, const __bf16* __restrict__ Bm,
    __bf16* __restrict__ C, float* __restrict__ rsum,
    int Nr, int Kr, int nTiles) {
  __shared__ __bf16 Als[2][256 * 32];  // 32 KB
  __shared__ __bf16 Bls[2][128 * 32];  // 16 KB
  const int tid = threadIdx.x;
  const int w = tid >> 6, l = tid & 63;
  const int f = blockIdx.x;
  int mb, nb;
  const int nT8 = (nTiles >> 3) << 3;
  if (f < 4 * nT8) {
    const int q = f >> 5, rem = f & 31;
    mb = rem >> 3;
    nb = q * 8 + (rem & 7);
  } else {
    const int r = f - 4 * nT8, tl = nTiles - nT8;
    mb = r / tl;
    nb = nT8 + r % tl;
  }
  const int m0 = mb * 256, n0 = nb * 128;
  const int nIt = Kr >> 5;

  int raA[4], caA[4], raB[2], caB[2], oA[4], oB[2];
#pragma unroll
  for (int g = 0; g < 4; ++g) {
    const int i = g * 256 + w * 64 + l;
    raA[g] = i >> 2;
    caA[g] = ((i & 3) ^ ((i >> 3) & 3)) * 8;
    oA[g] = (g * 256 + w * 64) * 8;
  }
#pragma unroll
  for (int g = 0; g < 2; ++g) {
    const int i = g * 256 + w * 64 + l;
    raB[g] = i >> 2;
    caB[g] = ((i & 3) ^ ((i >> 3) & 3)) * 8;
    oB[g] = (g * 256 + w * 64) * 8;
  }

  const int frow = l & 15, fq = l >> 4;
  const int fc = (fq ^ ((frow >> 1) & 3)) * 8;

  f32x4 acc[4][8];
  const f32x4 zero = {0.f, 0.f, 0.f, 0.f};
#pragma unroll
  for (int a = 0; a < 4; ++a)
#pragma unroll
    for (int b = 0; b < 8; ++b) acc[a][b] = zero;

  auto stage = [&](int buf, int it) {
    const size_t k0 = (size_t)it << 5;
#pragma unroll
    for (int g = 0; g < 4; ++g)
      async16(A + (size_t)(m0 + raA[g]) * Kr + caA[g] + k0, &Als[buf][oA[g]]);
#pragma unroll
    for (int g = 0; g < 2; ++g)
      async16(Bm + (size_t)(n0 + raB[g]) * Kr + caB[g] + k0, &Bls[buf][oB[g]]);
  };

  stage(0, 0);
  asm volatile("s_waitcnt vmcnt(0)" ::: "memory");
  __builtin_amdgcn_s_barrier();

  for (int it = 0; it < nIt; ++it) {
    const int cur = it & 1;
    if (it + 1 < nIt) stage(cur ^ 1, it + 1);
    bf16_8 af[4], bf[8];
#pragma unroll
    for (int mi = 0; mi < 4; ++mi)
      af[mi] = *(const bf16_8*)&Als[cur][(w * 64 + mi * 16 + frow) * 32 + fc];
#pragma unroll
    for (int ni = 0; ni < 8; ++ni)
      bf[ni] = *(const bf16_8*)&Bls[cur][(ni * 16 + frow) * 32 + fc];
#pragma unroll
    for (int mi = 0; mi < 4; ++mi)
#pragma unroll
      for (int ni = 0; ni < 8; ++ni)
        acc[mi][ni] = __builtin_amdgcn_mfma_f32_16x16x32_bf16(af[mi], bf[ni], acc[mi][ni], 0, 0, 0);
    asm volatile("s_waitcnt vmcnt(0) lgkmcnt(0)" ::: "memory");
    __builtin_amdgcn_s_barrier();
  }

#pragma unroll
  for (int mi = 0; mi < 4; ++mi) {
#pragma unroll
    for (int r = 0; r < 4; ++r) {
      const int row = m0 + w * 64 + mi * 16 + fq * 4 + r;
      float partial = 0.f;
#pragma unroll
      for (int ni = 0; ni < 8; ++ni) {
        const int col = n0 + ni * 16 + frow;
        const __bf16 h = (__bf16)exp2f(acc[mi][ni][r] * 1.4426950408889634f);
        C[(size_t)row * Nr + col] = h;
        partial += (float)h;
      }
#pragma unroll
      for (int off = 1; off < 16; off <<= 1) partial += __shfl_xor(partial, off, 64);
      if (frow == 0) atomicAdd(&rsum[row], partial);
    }
  }
}

// -------- batch zero: srcsum/qkv/ybuf/ybuf2/kw/hf/rs/pvacc in ONE launch ----------
__global__ __launch_bounds__(256) void zero8_k(float4* a0, float4* a1, float4* a2,
                                               float4* a3, float4* a4, float4* a5,
                                               float4* a6, float4* a7) {
  const int N0 = 196608, N1 = 589824, N2 = 196608, N3 = 196608, N4 = 131072,
            N5 = 786432, N6 = 256, N7 = 131072;
  const size_t total = (size_t)N0 + N1 + N2 + N3 + N4 + N5 + N6 + N7;
  const float4 z = {0.f, 0.f, 0.f, 0.f};
  for (size_t i = (size_t)blockIdx.x * 256 + threadIdx.x; i < total;
       i += (size_t)gridDim.x * 256) {
    size_t j = i;
    if (j < N0) { a0[j] = z; continue; } j -= N0;
    if (j < N1) { a1[j] = z; continue; } j -= N1;
    if (j < N2) { a2[j] = z; continue; } j -= N2;
    if (j < N3) { a3[j] = z; continue; } j -= N3;
    if (j < N4) { a4[j] = z; continue; } j -= N4;
    if (j < N5) { a5[j] = z; continue; } j -= N5;
    if (j < N6) { a6[j] = z; continue; } j -= N6;
    a7[j] = z;
  }
}

// -------- relu(hf + b1) -> bf16 hb (ffn1 split-K epilogue) ------------------------
__global__ __launch_bounds__(256) void relu_bf16_k(const float* __restrict__ hf,
                                                   const float* __restrict__ b1,
                                                   __bf16* __restrict__ hb) {
  const int i = blockIdx.x * 256 + threadIdx.x;  // over M_*FF_/4 = 786432 float4s
  const float4 v = ((const float4*)hf)[i];
  const int col4 = (i % 768) * 4;
  const float4 bb = *(const float4*)(b1 + col4);
  bf16x4 o;
  o[0] = (__bf16)fmaxf(v.x + bb.x, 0.f);
  o[1] = (__bf16)fmaxf(v.y + bb.y, 0.f);
  o[2] = (__bf16)fmaxf(v.z + bb.z, 0.f);
  o[3] = (__bf16)fmaxf(v.w + bb.w, 0.f);
  *(bf16x4*)(hb + (size_t)i * 4) = o;
}

// -------- unified weight prep: 7 transposes + bias concat in ONE launch -----------
__global__ __launch_bounds__(256) void prep_all_k(
    const float* __restrict__ wq, const float* __restrict__ wk,
    const float* __restrict__ wv, const float* __restrict__ wo,
    const float* __restrict__ w1, const float* __restrict__ w2,
    const float* __restrict__ wp,
    const float* __restrict__ bq, const float* __restrict__ bk,
    const float* __restrict__ bv,
    __bf16* __restrict__ wqkvT, __bf16* __restrict__ woT,
    __bf16* __restrict__ w1T, __bf16* __restrict__ w2T,
    __bf16* __restrict__ wpT, float* __restrict__ bqkv) {
  const int id = blockIdx.x;
  if (id >= 7296) {
    const int i = (id - 7296) * 256 + threadIdx.x;
    if (i < 768) bqkv[i] = bq[i];
    else if (i < 1536) bqkv[i] = bk[i - 768];
    else if (i < 2304) bqkv[i] = bv[i - 1536];
    return;
  }
  const float* src;
  __bf16* dst;
  int R, C, Cb, r;
  if (id < 2304) {
    const int seg = id / 576;
    r = id - seg * 576; R = 768; C = 768; Cb = 24;
    src = (seg == 0) ? wq : (seg == 1) ? wk : (seg == 2) ? wv : wo;
    dst = (seg == 3) ? woT : wqkvT + (size_t)seg * 768 * 768;
  } else if (id < 4608) {
    r = id - 2304; src = w1; dst = w1T; R = 768; C = 3072; Cb = 96;
  } else if (id < 6912) {
    r = id - 4608; src = w2; dst = w2T; R = 3072; C = 768; Cb = 24;
  } else {
    r = id - 6912; src = wp; dst = wpT; R = 768; C = 512; Cb = 16;
  }
  const int bx = r % Cb, by = r / Cb;
  __shared__ float tl[32][33];
  const int tx = threadIdx.x & 31, ty = threadIdx.x >> 5;
  const int c0 = bx * 32, r0 = by * 32;
#pragma unroll
  for (int k = 0; k < 4; ++k) {
    const int rr = ty + k * 8;
    tl[rr][tx] = src[(size_t)(r0 + rr) * C + (c0 + tx)];
  }
  __syncthreads();
#pragma unroll
  for (int k = 0; k < 4; ++k) {
    const int rr = ty + k * 8;
    dst[(size_t)(c0 + rr) * R + (r0 + tx)] = (__bf16)tl[tx][rr];
  }
}

// -------- emb prep: read fp32 emb once, write normalized bf16 + raw transpose -----
__global__ __launch_bounds__(256) void embprep_k(const float* __restrict__ emb,
                                                 __bf16* __restrict__ embn,
                                                 __bf16* __restrict__ embT, int nc) {
  __shared__ __bf16 tile[32][516];
  const int tid = threadIdx.x;
  const int r = tid >> 4, i = tid & 15;
  const int vloc = blockIdx.x * 32;
  float4 f[2][8];
  float ss[2] = {0.f, 0.f};
#pragma unroll
  for (int h = 0; h < 2; ++h) {
    const int v = vloc + r + h * 16;
    const float4* row = (const float4*)(emb + (size_t)v * 512);
#pragma unroll
    for (int j = 0; j < 8; ++j) {
      float4 x = row[i + j * 16];
      f[h][j] = x;
      ss[h] += x.x * x.x + x.y * x.y + x.z * x.z + x.w * x.w;
    }
  }
#pragma unroll
  for (int off = 1; off < 16; off <<= 1) {
    ss[0] += __shfl_xor(ss[0], off, 64);
    ss[1] += __shfl_xor(ss[1], off, 64);
  }
  float inv[2];
#pragma unroll
  for (int h = 0; h < 2; ++h) inv[h] = 1.f / fmaxf(sqrtf(ss[h]), 1e-8f);
#pragma unroll
  for (int h = 0; h < 2; ++h) {
    const int vr = r + h * 16;
#pragma unroll
    for (int j = 0; j < 8; ++j) {
      const int d4 = i + j * 16;
      float4 x = f[h][j];
      tile[vr][d4 * 4 + 0] = (__bf16)x.x;
      tile[vr][d4 * 4 + 1] = (__bf16)x.y;
      tile[vr][d4 * 4 + 2] = (__bf16)x.z;
      tile[vr][d4 * 4 + 3] = (__bf16)x.w;
      bf16x4 o;
      o[0] = (__bf16)(x.x * inv[h]);
      o[1] = (__bf16)(x.y * inv[h]);
      o[2] = (__bf16)(x.z * inv[h]);
      o[3] = (__bf16)(x.w * inv[h]);
      *(bf16x4*)(embn + (size_t)(vloc + vr) * 512 + d4 * 4) = o;
    }
  }
  __syncthreads();
#pragma unroll
  for (int c = 0; c < 2; ++c) {
    const int d = tid + c * 256;
    uint us[16];
#pragma unroll
    for (int v = 0; v < 32; v += 2) {
      __bf16 a = tile[v][d], b = tile[v + 1][d];
      us[v >> 1] = (uint)(*(unsigned short*)&a) | ((uint)(*(unsigned short*)&b) << 16);
    }
    uint4* dst = (uint4*)(embT + (size_t)d * nc + vloc);
#pragma unroll
    for (int q = 0; q < 4; ++q) {
      uint4 u = {us[q * 4], us[q * 4 + 1], us[q * 4 + 2], us[q * 4 + 3]};
      dst[q] = u;
    }
  }
}

// -------- segment pooling phase 1: chunked streaming partial sums (atomics) -------
__global__ __launch_bounds__(256) void seg_partial_k(
    const float* __restrict__ af, const int* __restrict__ align,
    const int* __restrict__ alen, float* __restrict__ srcsum) {
  __shared__ int ts_s[64], te_s[64], segid[SCH];
  const int b = blockIdx.x, ch = blockIdx.y;
  const int tid = threadIdx.x;
  if (tid < 64) {
    const int ts = align[(b * 64 + tid) * 2];
    const int te = align[(b * 64 + tid) * 2 + 1];
    const int teff = (te == alen[b]) ? T_ : te;
    ts_s[tid] = min(max(ts, 0), T_);
    te_s[tid] = min(max(teff, 0), T_);
  }
  __syncthreads();
  const int t0 = ch * SCH;
  if (tid < SCH) {
    const int t = t0 + tid;
    int s = -1;
    if (ts_s[0] <= t) {
      int lo = 0, hi = 63;
      while (lo < hi) {
        const int mid = (lo + hi + 1) >> 1;
        if (ts_s[mid] <= t) lo = mid; else hi = mid - 1;
      }
      s = (t < te_s[lo]) ? lo : -1;
    }
    segid[tid] = s;
  }
  __syncthreads();
  float a0 = 0.f, a1 = 0.f, a2 = 0.f;
  int cur = -1;
  for (int k = 0; k < SCH; ++k) {
    const int s = segid[k];
    if (s != cur) {
      if (cur >= 0) {
        float* dst = srcsum + (size_t)(b * 64 + cur) * 768 + tid;
        atomicAdd(dst, a0); atomicAdd(dst + 256, a1); atomicAdd(dst + 512, a2);
      }
      a0 = a1 = a2 = 0.f;
      cur = s;
    }
    if (s >= 0) {
      const float* row = af + ((size_t)b * T_ + t0 + k) * 768 + tid;
      a0 += row[0]; a1 += row[256]; a2 += row[512];
    }
  }
  if (cur >= 0) {
    float* dst = srcsum + (size_t)(b * 64 + cur) * 768 + tid;
    atomicAdd(dst, a0); atomicAdd(dst + 256, a1); atomicAdd(dst + 512, a2);
  }
}

// -------- segment pooling phase 2: mean + mask + LayerNorm ------------------------
__global__ __launch_bounds__(256) void pool_fin_k(
    const float* __restrict__ srcsum, const int* __restrict__ align,
    const int* __restrict__ alen, const int* __restrict__ anum,
    const float* __restrict__ g, const float* __restrict__ be,
    float* __restrict__ srcf, __bf16* __restrict__ srcb) {
  __shared__ float red[4];
  const int m = blockIdx.x, b = m >> 6, s = m & 63;
  const int tid = threadIdx.x;
  const int ts = align[m * 2], te = align[m * 2 + 1];
  const bool valid = (ts >= 0) && (s < anum[b]);
  const int teff = (te == alen[b]) ? T_ : te;
  const int tsc = min(max(ts, 0), T_), tec = min(max(teff, 0), T_);
  const float invc = 1.f / (float)max(tec - tsc, 1);
  float x[3];
#pragma unroll
  for (int u = 0; u < 3; ++u) {
    const int d = tid + u * 256;
    x[u] = valid ? srcsum[(size_t)m * 768 + d] * invc : 0.f;
  }
  const float mean = blk_sum256(x[0] + x[1] + x[2], red) * (1.f / 768.f);
  float lv = 0.f;
#pragma unroll
  for (int u = 0; u < 3; ++u) { float dd = x[u] - mean; lv += dd * dd; }
  const float var = blk_sum256(lv, red) * (1.f / 768.f);
  const float rstd = rsqrtf(var + 1e-5f);
#pragma unroll
  for (int u = 0; u < 3; ++u) {
    const int d = tid + u * 256;
    const float o = (x[u] - mean) * rstd * g[d] + be[d];
    srcf[(size_t)m * 768 + d] = o;
    srcb[(size_t)m * 768 + d] = (__bf16)o;
  }
}

// -------- residual add + column-bias + LayerNorm ----------------------------------
__global__ __launch_bounds__(256) void add_ln_k(
    const float* __restrict__ a, const float* __restrict__ r,
    const float* __restrict__ cb,
    const float* __restrict__ g, const float* __restrict__ be,
    float* __restrict__ outf, __bf16* __restrict__ outb) {
  __shared__ float red[4];
  const int m = blockIdx.x, tid = threadIdx.x;
  float x[3];
#pragma unroll
  for (int u = 0; u < 3; ++u) {
    const int d = tid + u * 256;
    const size_t idx = (size_t)m * 768 + d;
    x[u] = a[idx] + (r ? r[idx] : 0.f) + (cb ? cb[d] : 0.f);
  }
  const float mean = blk_sum256(x[0] + x[1] + x[2], red) * (1.f / 768.f);
  float lv = 0.f;
#pragma unroll
  for (int u = 0; u < 3; ++u) { float dd = x[u] - mean; lv += dd * dd; }
  const float var = blk_sum256(lv, red) * (1.f / 768.f);
  const float rstd = rsqrtf(var + 1e-5f);
#pragma unroll
  for (int u = 0; u < 3; ++u) {
    const int d = tid + u * 256;
    const float o = (x[u] - mean) * rstd * g[d] + be[d];
    if (outf) outf[(size_t)m * 768 + d] = o;
    if (outb) outb[(size_t)m * 768 + d] = (__bf16)o;
  }
}

// -------- attention (MFMA): one block per (b,h), 4 waves x 16 Q-rows each ---------
__global__ __launch_bounds__(256) void attn_k(const float* __restrict__ qkv,
                                              const float* __restrict__ bqkv,
                                              const int* __restrict__ anum,
                                              __bf16* __restrict__ ctx) {
  __shared__ __bf16 vt[96 * 72];     // V^T [d][key]
  __shared__ __bf16 pl[4][16 * 72];  // per-wave P [row][key]
  const int tid = threadIdx.x;
  const int w = tid >> 6, l = tid & 63;
  const int frow = l & 15, fq = l >> 4;
  const int b = blockIdx.x >> 3, h = blockIdx.x & 7;
  const int colq = h * 96;
  const f32x4 zero = {0.f, 0.f, 0.f, 0.f};

  for (int idx = tid; idx < 6144; idx += 256) {
    const int key = idx / 96, d = idx - key * 96;
    const float v = qkv[((size_t)(b * 64 + key)) * 2304 + 1536 + colq + d] +
                    bqkv[1536 + colq + d];
    vt[d * 72 + key] = (__bf16)v;
  }

  bf16_8 qf[3];
  {
    const float* qr = qkv + ((size_t)(b * 64 + 16 * w + frow)) * 2304 + colq;
#pragma unroll
    for (int kf = 0; kf < 3; ++kf) {
      const int c = kf * 32 + fq * 8;
      bf16_8 t;
#pragma unroll
      for (int j = 0; j < 8; ++j) t[j] = (__bf16)(qr[c + j] + bqkv[colq + c + j]);
      qf[kf] = t;
    }
  }
  bf16_8 kfr[4][3];
#pragma unroll
  for (int ni = 0; ni < 4; ++ni) {
    const float* kr = qkv + ((size_t)(b * 64 + ni * 16 + frow)) * 2304 + 768 + colq;
#pragma unroll
    for (int kf = 0; kf < 3; ++kf) {
      const int c = kf * 32 + fq * 8;
      bf16_8 t;
#pragma unroll
      for (int j = 0; j < 8; ++j) t[j] = (__bf16)(kr[c + j] + bqkv[768 + colq + c + j]);
      kfr[ni][kf] = t;
    }
  }

  f32x4 s[4];
#pragma unroll
  for (int ni = 0; ni < 4; ++ni) {
    s[ni] = zero;
#pragma unroll
    for (int kf = 0; kf < 3; ++kf)
      s[ni] = __builtin_amdgcn_mfma_f32_16x16x32_bf16(qf[kf], kfr[ni][kf], s[ni], 0, 0, 0);
  }

  const int an = anum[b];
#pragma unroll
  for (int r = 0; r < 4; ++r) {
    float v4[4];
    float mx = -3.4e38f;
#pragma unroll
    for (int ni = 0; ni < 4; ++ni) {
      const int col = ni * 16 + frow;
      float v = s[ni][r] * 0.10206207261596577f;  // 1/sqrt(96)
      if (col >= an) v = -1e30f;
      v4[ni] = v;
      mx = fmaxf(mx, v);
    }
#pragma unroll
    for (int o = 1; o < 16; o <<= 1) mx = fmaxf(mx, __shfl_xor(mx, o, 64));
    float sum = 0.f;
#pragma unroll
    for (int ni = 0; ni < 4; ++ni) {
      v4[ni] = exp2f((v4[ni] - mx) * 1.4426950408889634f);
      sum += v4[ni];
    }
#pragma unroll
    for (int o = 1; o < 16; o <<= 1) sum += __shfl_xor(sum, o, 64);
    const float inv = 1.f / sum;
    const int prow = (fq * 4 + r) * 72;
#pragma unroll
    for (int ni = 0; ni < 4; ++ni)
      pl[w][prow + ni * 16 + frow] = (__bf16)(v4[ni] * inv);
  }

  __syncthreads();

  bf16_8 pa[2];
#pragma unroll
  for (int ks = 0; ks < 2; ++ks)
    pa[ks] = *(const bf16_8*)&pl[w][frow * 72 + ks * 32 + fq * 8];
#pragma unroll
  for (int dj = 0; dj < 6; ++dj) {
    f32x4 o = zero;
#pragma unroll
    for (int ks = 0; ks < 2; ++ks) {
      bf16_8 vb = *(const bf16_8*)&vt[(dj * 16 + frow) * 72 + ks * 32 + fq * 8];
      o = __builtin_amdgcn_mfma_f32_16x16x32_bf16(pa[ks], vb, o, 0, 0, 0);
    }
#pragma unroll
    for (int r = 0; r < 4; ++r)
      ctx[((size_t)(b * 64 + 16 * w + fq * 4 + r)) * 768 + colq + dj * 16 + frow] =
          (__bf16)o[r];
  }
}

// -------- row L2-normalize (512-wide) fp32 (+bias) -> bf16 (for kw) ---------------
__global__ __launch_bounds__(256) void l2norm_bf16_k(const float* __restrict__ src,
                                                     const float* __restrict__ cb,
                                                     __bf16* __restrict__ dst) {
  __shared__ float red[4];
  const int rix = blockIdx.x, tid = threadIdx.x;
  const float* row = src + (size_t)rix * 512;
  const float v0 = row[tid] + cb[tid];
  const float v1 = row[tid + 256] + cb[tid + 256];
  const float tot = blk_sum256(v0 * v0 + v1 * v1, red);
  const float inv = 1.f / fmaxf(sqrtf(tot), 1e-8f);
  dst[(size_t)rix * 512 + tid] = (__bf16)(v0 * inv);
  dst[(size_t)rix * 512 + tid + 256] = (__bf16)(v1 * inv);
}

// -------- final: scale L2-resident accumulator by 1/rowsum ------------------------
__global__ __launch_bounds__(256) void final_scale_k(const float* __restrict__ pvacc,
                                                     const float* __restrict__ rs,
                                                     float* __restrict__ out) {
  const int m = blockIdx.x, d = threadIdx.x;
  const float inv = 1.f / rs[m];
  out[(size_t)m * TD_ + d] = pvacc[(size_t)m * TD_ + d] * inv;
  out[(size_t)m * TD_ + d + 256] = pvacc[(size_t)m * TD_ + d + 256] * inv;
}

extern "C" void kernel_launch(void* const* d_in, const int* in_sizes, int n_in,
                              void* d_out, int out_size, void* d_ws, size_t ws_size,
                              hipStream_t stream) {
  const float* audio = (const float*)d_in[0];
  const float* ln1g = (const float*)d_in[1];
  const float* ln1b = (const float*)d_in[2];
  const float* wq = (const float*)d_in[3];
  const float* bq = (const float*)d_in[4];
  const float* wk = (const float*)d_in[5];
  const float* bk = (const float*)d_in[6];
  const float* wv = (const float*)d_in[7];
  const float* bv = (const float*)d_in[8];
  const float* wo = (const float*)d_in[9];
  const float* bo = (const float*)d_in[10];
  const float* lnag = (const float*)d_in[11];
  const float* lnab = (const float*)d_in[12];
  const float* w1 = (const float*)d_in[13];
  const float* b1 = (const float*)d_in[14];
  const float* w2 = (const float*)d_in[15];
  const float* b2 = (const float*)d_in[16];
  const float* lnbg = (const float*)d_in[17];
  const float* lnbb = (const float*)d_in[18];
  const float* wp = (const float*)d_in[19];
  const float* bp = (const float*)d_in[20];
  const float* emb = (const float*)d_in[21];
  const int* alen = (const int*)d_in[22];
  const int* align = (const int*)d_in[23];
  const int* anum = (const int*)d_in[24];
  float* out = (float*)d_out;

  char* p = (char*)d_ws;
  auto alloc = [&](size_t bytes) {
    char* r = p;
    p += (bytes + 255) & ~(size_t)255;
    return r;
  };
  // --- overlay: transformer temporaries (dead by vocab stage) ---
  float* srcsum = (float*)alloc((size_t)M_ * 768 * 4);
  float* srcf = (float*)alloc((size_t)M_ * 768 * 4);
  __bf16* srcb = (__bf16*)alloc((size_t)M_ * 768 * 2);
  float* qkv = (float*)alloc((size_t)M_ * 2304 * 4);
  __bf16* ctxb = (__bf16*)alloc((size_t)M_ * 768 * 2);
  float* ybuf = (float*)alloc((size_t)M_ * 768 * 4);
  float* ybuf2 = (float*)alloc((size_t)M_ * 768 * 4);
  float* xf = (float*)alloc((size_t)M_ * 768 * 4);
  __bf16* xb = (__bf16*)alloc((size_t)M_ * 768 * 2);
  float* hf = (float*)alloc((size_t)M_ * FF_ * 4);
  __bf16* hb = (__bf16*)alloc((size_t)M_ * FF_ * 2);
  __bf16* x2b = (__bf16*)alloc((size_t)M_ * 768 * 2);
  float* kw = (float*)alloc((size_t)M_ * 512 * 4);
  // --- persistent-through-vocab allocations ---
  __bf16* kwn = (__bf16*)alloc((size_t)M_ * 512 * 2);
  float* rs = (float*)alloc((size_t)M_ * 4);
  float* pvacc = (float*)alloc((size_t)M_ * TD_ * 4);  // L2-resident PV accumulator
  __bf16* wqkvT = (__bf16*)alloc((size_t)2304 * 768 * 2);
  __bf16* woT = (__bf16*)alloc((size_t)768 * 768 * 2);
  __bf16* w1T = (__bf16*)alloc((size_t)3072 * 768 * 2);
  __bf16* w2T = (__bf16*)alloc((size_t)768 * 3072 * 2);
  __bf16* wpT = (__bf16*)alloc((size_t)512 * 768 * 2);
  float* bqkv = (float*)alloc((size_t)2304 * 4);

  const size_t used = (size_t)(p - (char*)d_ws);
  const size_t avail = (ws_size > used + 4096) ? (ws_size - used - 4096) : 0;
  const size_t perTile = ((size_t)128 * 512 * 2) * 2 + (size_t)1024 * 128 * 2;
  size_t tp = avail / perTile;
  if (tp < 1) tp = 1;
  if (tp > 386) tp = 386;
  const int tilesPer = (int)tp;
  const int nChunks = (386 + tilesPer - 1) / tilesPer;
  const int maxCols = tilesPer * 128;
  __bf16* embnC = (__bf16*)alloc((size_t)maxCols * 512 * 2);
  __bf16* embTC = (__bf16*)alloc((size_t)512 * maxCols * 2);
  __bf16* Ec = (__bf16*)alloc((size_t)1024 * maxCols * 2);

  // one batched zero for srcsum/qkv/ybuf/ybuf2/kw/hf/rs/pvacc
  zero8_k<<<2048, 256, 0, stream>>>((float4*)srcsum, (float4*)qkv, (float4*)ybuf,
                                    (float4*)ybuf2, (float4*)kw, (float4*)hf,
                                    (float4*)rs, (float4*)pvacc);

  // weight prep (single launch)
  prep_all_k<<<7305, 256, 0, stream>>>(wq, wk, wv, wo, w1, w2, wp, bq, bk, bv,
                                       wqkvT, woT, w1T, w2T, wpT, bqkv);

  // pooling + transformer (split-K MODE 6, z in {2,4}: measured optimum R12)
  seg_partial_k<<<dim3(16, T_ / SCH), 256, 0, stream>>>(audio, align, alen, srcsum);
  pool_fin_k<<<M_, 256, 0, stream>>>(srcsum, align, alen, anum, ln1g, ln1b, srcf, srcb);
  gemm_nt<6, 0><<<dim3(8, 18, 2), 256, 0, stream>>>(srcb, wqkvT, nullptr, qkv, 2304, 768, 12);
  attn_k<<<128, 256, 0, stream>>>(qkv, bqkv, anum, ctxb);
  gemm_nt<6, 0><<<dim3(8, 6, 2), 256, 0, stream>>>(ctxb, woT, nullptr, ybuf, 768, 768, 12);
  add_ln_k<<<M_, 256, 0, stream>>>(ybuf, srcf, bo, lnag, lnab, xf, xb);
  gemm_nt<6, 0><<<dim3(8, 24, 2), 256, 0, stream>>>(xb, w1T, nullptr, hf, 3072, 768, 12);
  relu_bf16_k<<<3072, 256, 0, stream>>>(hf, b1, hb);
  gemm_nt<6, 0><<<dim3(8, 6, 4), 256, 0, stream>>>(hb, w2T, nullptr, ybuf2, 768, 3072, 24);
  add_ln_k<<<M_, 256, 0, stream>>>(ybuf2, xf, b2, lnbg, lnbb, nullptr, x2b);
  gemm_nt<6, 0><<<dim3(8, 4, 4), 256, 0, stream>>>(x2b, wpT, nullptr, kw, 512, 768, 6);
  l2norm_bf16_k<<<M_, 256, 0, stream>>>(kw, bp, kwn);

  // vocab stage: E = exp(cos) (bf16) -> PV atomically accumulates into pvacc (2 MB,
  // L2-resident) -> final scale. No 64 MB slice round-trip.
  if (nChunks == 1) {
    embprep_k<<<V_ / 32, 256, 0, stream>>>(emb, embnC, embTC, V_);
    gemm_big_exp<<<4 * 386, 256, 0, stream>>>(kwn, embnC, Ec, rs, V_, 512, 386);
    const int kpz = (V_ / 32 + ZSL - 1) / ZSL;  // 49
    gemm_nt<6, 2><<<1024, 256, 0, stream>>>(Ec, embTC, nullptr, pvacc, 512, V_, kpz);
  } else {
    for (int c = 0; c < nChunks; ++c) {
      const int t0 = c * tilesPer;
      const int nt = min(tilesPer, 386 - t0);
      const int v0 = t0 * 128, nc = nt * 128;
      embprep_k<<<nc / 32, 256, 0, stream>>>(emb + (size_t)v0 * 512, embnC, embTC, nc);
      gemm_big_exp<<<4 * nt, 256, 0, stream>>>(kwn, embnC, Ec, rs, nc, 512, nt);
      const int totIt = nc >> 5;
      const int kpz = (totIt + ZSL - 1) / ZSL;
      gemm_nt<6, 0><<<dim3(8, 4, ZSL), 256, 0, stream>>>(Ec, embTC, nullptr, pvacc, 512, nc, kpz);
    }
  }
  final_scale_k<<<M_, 256, 0, stream>>>(pvacc, rs, out);
}

// Round 16
// 618.224 us; speedup vs baseline: 1.0230x; 1.0230x over previous
//
#include <hip/hip_runtime.h>
#include <hip/hip_bf16.h>
#include <math.h>

#define B_  16
#define T_  1024
#define D_  768
#define S_  64
#define H_  8
#define DH_ 96
#define FF_ 3072
#define TD_ 512
#define V_  49408
#define M_  1024  // B_*S_
#define ZSL 32
#define SCH 32    // seg_partial frames per chunk

typedef __bf16 bf16_8 __attribute__((ext_vector_type(8)));
typedef __bf16 bf16x4 __attribute__((ext_vector_type(4)));
typedef float f32x4 __attribute__((ext_vector_type(4)));

__device__ __forceinline__ void async16(const void* g, void* lds) {
  __builtin_amdgcn_global_load_lds((const __attribute__((address_space(1))) void*)g,
                                   (__attribute__((address_space(3))) void*)lds,
                                   16, 0, 0);
}

__device__ __forceinline__ float blk_sum256(float v, float* red) {
#pragma unroll
  for (int o = 32; o > 0; o >>= 1) v += __shfl_down(v, o, 64);
  const int w = threadIdx.x >> 6;
  if ((threadIdx.x & 63) == 0) red[w] = v;
  __syncthreads();
  float t = red[0] + red[1] + red[2] + red[3];
  __syncthreads();
  return t;
}

// ---------------- GEMM 128x128: C[M,N] = A[M,K](bf16) * B[N,K]^T(bf16) ------------
// MODE 0: fp32 out (+bias)  1: relu bf16 out (+bias)
// MODE 4: fp32 write to private z-slice  5: read-add-write to private z-slice
// MODE 6: fp32 atomicAdd into shared output (split-K; bias handled by consumer)
// SWZ=2: grid (1024,1,1); XCD x owns z in {4x..4x+3} entirely (8 mb x 4 nb each).
// 2-phase double-buffered pipeline (proven). launch_bounds(256,4): 4 blocks/CU.
// Split-K z tuned to z in {2,4}: z=8 overhead-dominated (R13); shared-atomic
// accumulator for PV (32 writers/address) contention-dominated (R15).
template <int MODE, int SWZ>
__global__ __launch_bounds__(256, 4) void gemm_nt(
    const __bf16* __restrict__ A, const __bf16* __restrict__ Bm,
    const float* __restrict__ bias, void* __restrict__ Cv,
    int Nr, int Kr, int kIterPerZ) {
  __shared__ __bf16 Als[2][128 * 32];
  __shared__ __bf16 Bls[2][128 * 32];
  const int tid = threadIdx.x;
  const int w = tid >> 6, l = tid & 63;
  int mb, nb, zb;
  if (SWZ == 2) {
    const int f = blockIdx.x;          // [0,1024)
    const int x = f & 7, o = f >> 3;   // XCD x owns z = 4x + (o>>5)
    zb = 4 * x + (o >> 5);
    const int r = o & 31;
    mb = r >> 2;                       // 0..7 (A-tile reused across 4 nb)
    nb = r & 3;                        // 0..3
  } else {
    mb = blockIdx.x; nb = blockIdx.y; zb = blockIdx.z;
  }
  const int m0 = mb * 128, n0 = nb * 128;
  const int totIt = Kr >> 5;
  const int it0 = zb * kIterPerZ;
  const int nIt = min(kIterPerZ, totIt - it0);
  if (nIt <= 0) return;

  const int i0 = w * 128 + l, i1 = i0 + 64;
  const int ra0 = i0 >> 2, ca0 = ((i0 & 3) ^ ((i0 >> 3) & 3)) * 8;
  const int ra1 = i1 >> 2, ca1 = ((i1 & 3) ^ ((i1 >> 3) & 3)) * 8;
  const __bf16* gA0 = A + (size_t)(m0 + ra0) * Kr + ca0;
  const __bf16* gA1 = A + (size_t)(m0 + ra1) * Kr + ca1;
  const __bf16* gB0 = Bm + (size_t)(n0 + ra0) * Kr + ca0;
  const __bf16* gB1 = Bm + (size_t)(n0 + ra1) * Kr + ca1;
  const int o0 = (w * 128 + 0) * 8;
  const int o1 = (w * 128 + 64) * 8;

  const int wm = (w & 1) * 64, wn = (w >> 1) * 64;
  const int frow = l & 15, fq = l >> 4;
  const int fc = (fq ^ ((frow >> 1) & 3)) * 8;

  f32x4 acc[4][4];
  const f32x4 zero = {0.f, 0.f, 0.f, 0.f};
#pragma unroll
  for (int a = 0; a < 4; ++a)
#pragma unroll
    for (int b = 0; b < 4; ++b) acc[a][b] = zero;

  auto stage = [&](int buf, int it) {
    const size_t k0 = (size_t)(it0 + it) << 5;
    async16(gA0 + k0, &Als[buf][o0]);
    async16(gA1 + k0, &Als[buf][o1]);
    async16(gB0 + k0, &Bls[buf][o0]);
    async16(gB1 + k0, &Bls[buf][o1]);
  };

  stage(0, 0);
  asm volatile("s_waitcnt vmcnt(0)" ::: "memory");
  __builtin_amdgcn_s_barrier();

  for (int it = 0; it < nIt; ++it) {
    const int cur = it & 1;
    if (it + 1 < nIt) stage(cur ^ 1, it + 1);
    bf16_8 af[4], bf[4];
#pragma unroll
    for (int mi = 0; mi < 4; ++mi)
      af[mi] = *(const bf16_8*)&Als[cur][(wm + mi * 16 + frow) * 32 + fc];
#pragma unroll
    for (int ni = 0; ni < 4; ++ni)
      bf[ni] = *(const bf16_8*)&Bls[cur][(wn + ni * 16 + frow) * 32 + fc];
#pragma unroll
    for (int mi = 0; mi < 4; ++mi)
#pragma unroll
      for (int ni = 0; ni < 4; ++ni)
        acc[mi][ni] = __builtin_amdgcn_mfma_f32_16x16x32_bf16(af[mi], bf[ni], acc[mi][ni], 0, 0, 0);
    asm volatile("s_waitcnt vmcnt(0) lgkmcnt(0)" ::: "memory");
    __builtin_amdgcn_s_barrier();
  }

  float* Cs = (float*)Cv;
  if (MODE == 4 || MODE == 5) Cs += (size_t)zb * M_ * TD_;
#pragma unroll
  for (int mi = 0; mi < 4; ++mi) {
#pragma unroll
    for (int r = 0; r < 4; ++r) {
      const int row = m0 + wm + mi * 16 + fq * 4 + r;
#pragma unroll
      for (int ni = 0; ni < 4; ++ni) {
        const int col = n0 + wn + ni * 16 + frow;
        float v = acc[mi][ni][r];
        if (MODE == 0) {
          if (bias) v += bias[col];
          Cs[(size_t)row * Nr + col] = v;
        } else if (MODE == 1) {
          v += bias[col];
          ((__bf16*)Cv)[(size_t)row * Nr + col] = (__bf16)fmaxf(v, 0.f);
        } else if (MODE == 4) {
          Cs[(size_t)row * Nr + col] = v;
        } else if (MODE == 5) {
          Cs[(size_t)row * Nr + col] += v;
        } else {
          atomicAdd(&Cs[(size_t)row * Nr + col], v);
        }
      }
    }
  }
}

// ---------------- GEMM 256x128 (GEMM1): exp epilogue + fused rowsum ---------------
// grid: 1-D, 4*nTiles blocks, XCD-swizzled. 2-phase pipeline. Proven: 113.7 us.
__global__ __launch_bounds__(256, 2) void gemm_big_exp(
    const __bf16* __restrict__ A, const __bf16* __restrict__ Bm,
    __bf16* __restrict__ C, float* __restrict__ rsum,
    int Nr, int Kr, int nTiles) {
  __shared__ __bf16 Als[2][256 * 32];  // 32 KB
  __shared__ __bf16 Bls[2][128 * 32];  // 16 KB
  const int tid = threadIdx.x;
  const int w = tid >> 6, l = tid & 63;
  const int f = blockIdx.x;
  int mb, nb;
  const int nT8 = (nTiles >> 3) << 3;
  if (f < 4 * nT8) {
    const int q = f >> 5, rem = f & 31;
    mb = rem >> 3;
    nb = q * 8 + (rem & 7);
  } else {
    const int r = f - 4 * nT8, tl = nTiles - nT8;
    mb = r / tl;
    nb = nT8 + r % tl;
  }
  const int m0 = mb * 256, n0 = nb * 128;
  const int nIt = Kr >> 5;

  int raA[4], caA[4], raB[2], caB[2], oA[4], oB[2];
#pragma unroll
  for (int g = 0; g < 4; ++g) {
    const int i = g * 256 + w * 64 + l;
    raA[g] = i >> 2;
    caA[g] = ((i & 3) ^ ((i >> 3) & 3)) * 8;
    oA[g] = (g * 256 + w * 64) * 8;
  }
#pragma unroll
  for (int g = 0; g < 2; ++g) {
    const int i = g * 256 + w * 64 + l;
    raB[g] = i >> 2;
    caB[g] = ((i & 3) ^ ((i >> 3) & 3)) * 8;
    oB[g] = (g * 256 + w * 64) * 8;
  }

  const int frow = l & 15, fq = l >> 4;
  const int fc = (fq ^ ((frow >> 1) & 3)) * 8;

  f32x4 acc[4][8];
  const f32x4 zero = {0.f, 0.f, 0.f, 0.f};
#pragma unroll
  for (int a = 0; a < 4; ++a)
#pragma unroll
    for (int b = 0; b < 8; ++b) acc[a][b] = zero;

  auto stage = [&](int buf, int it) {
    const size_t k0 = (size_t)it << 5;
#pragma unroll
    for (int g = 0; g < 4; ++g)
      async16(A + (size_t)(m0 + raA[g]) * Kr + caA[g] + k0, &Als[buf][oA[g]]);
#pragma unroll
    for (int g = 0; g < 2; ++g)
      async16(Bm + (size_t)(n0 + raB[g]) * Kr + caB[g] + k0, &Bls[buf][oB[g]]);
  };

  stage(0, 0);
  asm volatile("s_waitcnt vmcnt(0)" ::: "memory");
  __builtin_amdgcn_s_barrier();

  for (int it = 0; it < nIt; ++it) {
    const int cur = it & 1;
    if (it + 1 < nIt) stage(cur ^ 1, it + 1);
    bf16_8 af[4], bf[8];
#pragma unroll
    for (int mi = 0; mi < 4; ++mi)
      af[mi] = *(const bf16_8*)&Als[cur][(w * 64 + mi * 16 + frow) * 32 + fc];
#pragma unroll
    for (int ni = 0; ni < 8; ++ni)
      bf[ni] = *(const bf16_8*)&Bls[cur][(ni * 16 + frow) * 32 + fc];
#pragma unroll
    for (int mi = 0; mi < 4; ++mi)
#pragma unroll
      for (int ni = 0; ni < 8; ++ni)
        acc[mi][ni] = __builtin_amdgcn_mfma_f32_16x16x32_bf16(af[mi], bf[ni], acc[mi][ni], 0, 0, 0);
    asm volatile("s_waitcnt vmcnt(0) lgkmcnt(0)" ::: "memory");
    __builtin_amdgcn_s_barrier();
  }

#pragma unroll
  for (int mi = 0; mi < 4; ++mi) {
#pragma unroll
    for (int r = 0; r < 4; ++r) {
      const int row = m0 + w * 64 + mi * 16 + fq * 4 + r;
      float partial = 0.f;
#pragma unroll
      for (int ni = 0; ni < 8; ++ni) {
        const int col = n0 + ni * 16 + frow;
        const __bf16 h = (__bf16)exp2f(acc[mi][ni][r] * 1.4426950408889634f);
        C[(size_t)row * Nr + col] = h;
        partial += (float)h;
      }
#pragma unroll
      for (int off = 1; off < 16; off <<= 1) partial += __shfl_xor(partial, off, 64);
      if (frow == 0) atomicAdd(&rsum[row], partial);
    }
  }
}

// -------- batch zero: srcsum, qkv, ybuf, ybuf2, kw, hf, rs in ONE launch ----------
__global__ __launch_bounds__(256) void zero6_k(float4* a0, float4* a1, float4* a2,
                                               float4* a3, float4* a4, float4* a5,
                                               float4* a6) {
  const int N0 = 196608, N1 = 589824, N2 = 196608, N3 = 196608, N4 = 131072,
            N5 = 786432, N6 = 256;
  const size_t total = (size_t)N0 + N1 + N2 + N3 + N4 + N5 + N6;
  const float4 z = {0.f, 0.f, 0.f, 0.f};
  for (size_t i = (size_t)blockIdx.x * 256 + threadIdx.x; i < total;
       i += (size_t)gridDim.x * 256) {
    size_t j = i;
    if (j < N0) { a0[j] = z; continue; } j -= N0;
    if (j < N1) { a1[j] = z; continue; } j -= N1;
    if (j < N2) { a2[j] = z; continue; } j -= N2;
    if (j < N3) { a3[j] = z; continue; } j -= N3;
    if (j < N4) { a4[j] = z; continue; } j -= N4;
    if (j < N5) { a5[j] = z; continue; } j -= N5;
    a6[j] = z;
  }
}

// -------- relu(hf + b1) -> bf16 hb (ffn1 split-K epilogue) ------------------------
__global__ __launch_bounds__(256) void relu_bf16_k(const float* __restrict__ hf,
                                                   const float* __restrict__ b1,
                                                   __bf16* __restrict__ hb) {
  const int i = blockIdx.x * 256 + threadIdx.x;  // over M_*FF_/4 = 786432 float4s
  const float4 v = ((const float4*)hf)[i];
  const int col4 = (i % 768) * 4;
  const float4 bb = *(const float4*)(b1 + col4);
  bf16x4 o;
  o[0] = (__bf16)fmaxf(v.x + bb.x, 0.f);
  o[1] = (__bf16)fmaxf(v.y + bb.y, 0.f);
  o[2] = (__bf16)fmaxf(v.z + bb.z, 0.f);
  o[3] = (__bf16)fmaxf(v.w + bb.w, 0.f);
  *(bf16x4*)(hb + (size_t)i * 4) = o;
}

// -------- unified weight prep: 7 transposes + bias concat in ONE launch -----------
__global__ __launch_bounds__(256) void prep_all_k(
    const float* __restrict__ wq, const float* __restrict__ wk,
    const float* __restrict__ wv, const float* __restrict__ wo,
    const float* __restrict__ w1, const float* __restrict__ w2,
    const float* __restrict__ wp,
    const float* __restrict__ bq, const float* __restrict__ bk,
    const float* __restrict__ bv,
    __bf16* __restrict__ wqkvT, __bf16* __restrict__ woT,
    __bf16* __restrict__ w1T, __bf16* __restrict__ w2T,
    __bf16* __restrict__ wpT, float* __restrict__ bqkv) {
  const int id = blockIdx.x;
  if (id >= 7296) {
    const int i = (id - 7296) * 256 + threadIdx.x;
    if (i < 768) bqkv[i] = bq[i];
    else if (i < 1536) bqkv[i] = bk[i - 768];
    else if (i < 2304) bqkv[i] = bv[i - 1536];
    return;
  }
  const float* src;
  __bf16* dst;
  int R, C, Cb, r;
  if (id < 2304) {
    const int seg = id / 576;
    r = id - seg * 576; R = 768; C = 768; Cb = 24;
    src = (seg == 0) ? wq : (seg == 1) ? wk : (seg == 2) ? wv : wo;
    dst = (seg == 3) ? woT : wqkvT + (size_t)seg * 768 * 768;
  } else if (id < 4608) {
    r = id - 2304; src = w1; dst = w1T; R = 768; C = 3072; Cb = 96;
  } else if (id < 6912) {
    r = id - 4608; src = w2; dst = w2T; R = 3072; C = 768; Cb = 24;
  } else {
    r = id - 6912; src = wp; dst = wpT; R = 768; C = 512; Cb = 16;
  }
  const int bx = r % Cb, by = r / Cb;
  __shared__ float tl[32][33];
  const int tx = threadIdx.x & 31, ty = threadIdx.x >> 5;
  const int c0 = bx * 32, r0 = by * 32;
#pragma unroll
  for (int k = 0; k < 4; ++k) {
    const int rr = ty + k * 8;
    tl[rr][tx] = src[(size_t)(r0 + rr) * C + (c0 + tx)];
  }
  __syncthreads();
#pragma unroll
  for (int k = 0; k < 4; ++k) {
    const int rr = ty + k * 8;
    dst[(size_t)(c0 + rr) * R + (r0 + tx)] = (__bf16)tl[tx][rr];
  }
}

// -------- emb prep: read fp32 emb once, write normalized bf16 + raw transpose -----
__global__ __launch_bounds__(256) void embprep_k(const float* __restrict__ emb,
                                                 __bf16* __restrict__ embn,
                                                 __bf16* __restrict__ embT, int nc) {
  __shared__ __bf16 tile[32][516];
  const int tid = threadIdx.x;
  const int r = tid >> 4, i = tid & 15;
  const int vloc = blockIdx.x * 32;
  float4 f[2][8];
  float ss[2] = {0.f, 0.f};
#pragma unroll
  for (int h = 0; h < 2; ++h) {
    const int v = vloc + r + h * 16;
    const float4* row = (const float4*)(emb + (size_t)v * 512);
#pragma unroll
    for (int j = 0; j < 8; ++j) {
      float4 x = row[i + j * 16];
      f[h][j] = x;
      ss[h] += x.x * x.x + x.y * x.y + x.z * x.z + x.w * x.w;
    }
  }
#pragma unroll
  for (int off = 1; off < 16; off <<= 1) {
    ss[0] += __shfl_xor(ss[0], off, 64);
    ss[1] += __shfl_xor(ss[1], off, 64);
  }
  float inv[2];
#pragma unroll
  for (int h = 0; h < 2; ++h) inv[h] = 1.f / fmaxf(sqrtf(ss[h]), 1e-8f);
#pragma unroll
  for (int h = 0; h < 2; ++h) {
    const int vr = r + h * 16;
#pragma unroll
    for (int j = 0; j < 8; ++j) {
      const int d4 = i + j * 16;
      float4 x = f[h][j];
      tile[vr][d4 * 4 + 0] = (__bf16)x.x;
      tile[vr][d4 * 4 + 1] = (__bf16)x.y;
      tile[vr][d4 * 4 + 2] = (__bf16)x.z;
      tile[vr][d4 * 4 + 3] = (__bf16)x.w;
      bf16x4 o;
      o[0] = (__bf16)(x.x * inv[h]);
      o[1] = (__bf16)(x.y * inv[h]);
      o[2] = (__bf16)(x.z * inv[h]);
      o[3] = (__bf16)(x.w * inv[h]);
      *(bf16x4*)(embn + (size_t)(vloc + vr) * 512 + d4 * 4) = o;
    }
  }
  __syncthreads();
#pragma unroll
  for (int c = 0; c < 2; ++c) {
    const int d = tid + c * 256;
    uint us[16];
#pragma unroll
    for (int v = 0; v < 32; v += 2) {
      __bf16 a = tile[v][d], b = tile[v + 1][d];
      us[v >> 1] = (uint)(*(unsigned short*)&a) | ((uint)(*(unsigned short*)&b) << 16);
    }
    uint4* dst = (uint4*)(embT + (size_t)d * nc + vloc);
#pragma unroll
    for (int q = 0; q < 4; ++q) {
      uint4 u = {us[q * 4], us[q * 4 + 1], us[q * 4 + 2], us[q * 4 + 3]};
      dst[q] = u;
    }
  }
}

// -------- segment pooling phase 1: chunked streaming partial sums (atomics) -------
__global__ __launch_bounds__(256) void seg_partial_k(
    const float* __restrict__ af, const int* __restrict__ align,
    const int* __restrict__ alen, float* __restrict__ srcsum) {
  __shared__ int ts_s[64], te_s[64], segid[SCH];
  const int b = blockIdx.x, ch = blockIdx.y;
  const int tid = threadIdx.x;
  if (tid < 64) {
    const int ts = align[(b * 64 + tid) * 2];
    const int te = align[(b * 64 + tid) * 2 + 1];
    const int teff = (te == alen[b]) ? T_ : te;
    ts_s[tid] = min(max(ts, 0), T_);
    te_s[tid] = min(max(teff, 0), T_);
  }
  __syncthreads();
  const int t0 = ch * SCH;
  if (tid < SCH) {
    const int t = t0 + tid;
    int s = -1;
    if (ts_s[0] <= t) {
      int lo = 0, hi = 63;
      while (lo < hi) {
        const int mid = (lo + hi + 1) >> 1;
        if (ts_s[mid] <= t) lo = mid; else hi = mid - 1;
      }
      s = (t < te_s[lo]) ? lo : -1;
    }
    segid[tid] = s;
  }
  __syncthreads();
  float a0 = 0.f, a1 = 0.f, a2 = 0.f;
  int cur = -1;
  for (int k = 0; k < SCH; ++k) {
    const int s = segid[k];
    if (s != cur) {
      if (cur >= 0) {
        float* dst = srcsum + (size_t)(b * 64 + cur) * 768 + tid;
        atomicAdd(dst, a0); atomicAdd(dst + 256, a1); atomicAdd(dst + 512, a2);
      }
      a0 = a1 = a2 = 0.f;
      cur = s;
    }
    if (s >= 0) {
      const float* row = af + ((size_t)b * T_ + t0 + k) * 768 + tid;
      a0 += row[0]; a1 += row[256]; a2 += row[512];
    }
  }
  if (cur >= 0) {
    float* dst = srcsum + (size_t)(b * 64 + cur) * 768 + tid;
    atomicAdd(dst, a0); atomicAdd(dst + 256, a1); atomicAdd(dst + 512, a2);
  }
}

// -------- segment pooling phase 2: mean + mask + LayerNorm ------------------------
__global__ __launch_bounds__(256) void pool_fin_k(
    const float* __restrict__ srcsum, const int* __restrict__ align,
    const int* __restrict__ alen, const int* __restrict__ anum,
    const float* __restrict__ g, const float* __restrict__ be,
    float* __restrict__ srcf, __bf16* __restrict__ srcb) {
  __shared__ float red[4];
  const int m = blockIdx.x, b = m >> 6, s = m & 63;
  const int tid = threadIdx.x;
  const int ts = align[m * 2], te = align[m * 2 + 1];
  const bool valid = (ts >= 0) && (s < anum[b]);
  const int teff = (te == alen[b]) ? T_ : te;
  const int tsc = min(max(ts, 0), T_), tec = min(max(teff, 0), T_);
  const float invc = 1.f / (float)max(tec - tsc, 1);
  float x[3];
#pragma unroll
  for (int u = 0; u < 3; ++u) {
    const int d = tid + u * 256;
    x[u] = valid ? srcsum[(size_t)m * 768 + d] * invc : 0.f;
  }
  const float mean = blk_sum256(x[0] + x[1] + x[2], red) * (1.f / 768.f);
  float lv = 0.f;
#pragma unroll
  for (int u = 0; u < 3; ++u) { float dd = x[u] - mean; lv += dd * dd; }
  const float var = blk_sum256(lv, red) * (1.f / 768.f);
  const float rstd = rsqrtf(var + 1e-5f);
#pragma unroll
  for (int u = 0; u < 3; ++u) {
    const int d = tid + u * 256;
    const float o = (x[u] - mean) * rstd * g[d] + be[d];
    srcf[(size_t)m * 768 + d] = o;
    srcb[(size_t)m * 768 + d] = (__bf16)o;
  }
}

// -------- residual add + column-bias + LayerNorm ----------------------------------
__global__ __launch_bounds__(256) void add_ln_k(
    const float* __restrict__ a, const float* __restrict__ r,
    const float* __restrict__ cb,
    const float* __restrict__ g, const float* __restrict__ be,
    float* __restrict__ outf, __bf16* __restrict__ outb) {
  __shared__ float red[4];
  const int m = blockIdx.x, tid = threadIdx.x;
  float x[3];
#pragma unroll
  for (int u = 0; u < 3; ++u) {
    const int d = tid + u * 256;
    const size_t idx = (size_t)m * 768 + d;
    x[u] = a[idx] + (r ? r[idx] : 0.f) + (cb ? cb[d] : 0.f);
  }
  const float mean = blk_sum256(x[0] + x[1] + x[2], red) * (1.f / 768.f);
  float lv = 0.f;
#pragma unroll
  for (int u = 0; u < 3; ++u) { float dd = x[u] - mean; lv += dd * dd; }
  const float var = blk_sum256(lv, red) * (1.f / 768.f);
  const float rstd = rsqrtf(var + 1e-5f);
#pragma unroll
  for (int u = 0; u < 3; ++u) {
    const int d = tid + u * 256;
    const float o = (x[u] - mean) * rstd * g[d] + be[d];
    if (outf) outf[(size_t)m * 768 + d] = o;
    if (outb) outb[(size_t)m * 768 + d] = (__bf16)o;
  }
}

// -------- attention (MFMA): one block per (b,h), 4 waves x 16 Q-rows each ---------
__global__ __launch_bounds__(256) void attn_k(const float* __restrict__ qkv,
                                              const float* __restrict__ bqkv,
                                              const int* __restrict__ anum,
                                              __bf16* __restrict__ ctx) {
  __shared__ __bf16 vt[96 * 72];     // V^T [d][key]
  __shared__ __bf16 pl[4][16 * 72];  // per-wave P [row][key]
  const int tid = threadIdx.x;
  const int w = tid >> 6, l = tid & 63;
  const int frow = l & 15, fq = l >> 4;
  const int b = blockIdx.x >> 3, h = blockIdx.x & 7;
  const int colq = h * 96;
  const f32x4 zero = {0.f, 0.f, 0.f, 0.f};

  for (int idx = tid; idx < 6144; idx += 256) {
    const int key = idx / 96, d = idx - key * 96;
    const float v = qkv[((size_t)(b * 64 + key)) * 2304 + 1536 + colq + d] +
                    bqkv[1536 + colq + d];
    vt[d * 72 + key] = (__bf16)v;
  }

  bf16_8 qf[3];
  {
    const float* qr = qkv + ((size_t)(b * 64 + 16 * w + frow)) * 2304 + colq;
#pragma unroll
    for (int kf = 0; kf < 3; ++kf) {
      const int c = kf * 32 + fq * 8;
      bf16_8 t;
#pragma unroll
      for (int j = 0; j < 8; ++j) t[j] = (__bf16)(qr[c + j] + bqkv[colq + c + j]);
      qf[kf] = t;
    }
  }
  bf16_8 kfr[4][3];
#pragma unroll
  for (int ni = 0; ni < 4; ++ni) {
    const float* kr = qkv + ((size_t)(b * 64 + ni * 16 + frow)) * 2304 + 768 + colq;
#pragma unroll
    for (int kf = 0; kf < 3; ++kf) {
      const int c = kf * 32 + fq * 8;
      bf16_8 t;
#pragma unroll
      for (int j = 0; j < 8; ++j) t[j] = (__bf16)(kr[c + j] + bqkv[768 + colq + c + j]);
      kfr[ni][kf] = t;
    }
  }

  f32x4 s[4];
#pragma unroll
  for (int ni = 0; ni < 4; ++ni) {
    s[ni] = zero;
#pragma unroll
    for (int kf = 0; kf < 3; ++kf)
      s[ni] = __builtin_amdgcn_mfma_f32_16x16x32_bf16(qf[kf], kfr[ni][kf], s[ni], 0, 0, 0);
  }

  const int an = anum[b];
#pragma unroll
  for (int r = 0; r < 4; ++r) {
    float v4[4];
    float mx = -3.4e38f;
#pragma unroll
    for (int ni = 0; ni < 4; ++ni) {
      const int col = ni * 16 + frow;
      float v = s[ni][r] * 0.10206207261596577f;  // 1/sqrt(96)
      if (col >= an) v = -1e30f;
      v4[ni] = v;
      mx = fmaxf(mx, v);
    }
#pragma unroll
    for (int o = 1; o < 16; o <<= 1) mx = fmaxf(mx, __shfl_xor(mx, o, 64));
    float sum = 0.f;
#pragma unroll
    for (int ni = 0; ni < 4; ++ni) {
      v4[ni] = exp2f((v4[ni] - mx) * 1.4426950408889634f);
      sum += v4[ni];
    }
#pragma unroll
    for (int o = 1; o < 16; o <<= 1) sum += __shfl_xor(sum, o, 64);
    const float inv = 1.f / sum;
    const int prow = (fq * 4 + r) * 72;
#pragma unroll
    for (int ni = 0; ni < 4; ++ni)
      pl[w][prow + ni * 16 + frow] = (__bf16)(v4[ni] * inv);
  }

  __syncthreads();

  bf16_8 pa[2];
#pragma unroll
  for (int ks = 0; ks < 2; ++ks)
    pa[ks] = *(const bf16_8*)&pl[w][frow * 72 + ks * 32 + fq * 8];
#pragma unroll
  for (int dj = 0; dj < 6; ++dj) {
    f32x4 o = zero;
#pragma unroll
    for (int ks = 0; ks < 2; ++ks) {
      bf16_8 vb = *(const bf16_8*)&vt[(dj * 16 + frow) * 72 + ks * 32 + fq * 8];
      o = __builtin_amdgcn_mfma_f32_16x16x32_bf16(pa[ks], vb, o, 0, 0, 0);
    }
#pragma unroll
    for (int r = 0; r < 4; ++r)
      ctx[((size_t)(b * 64 + 16 * w + fq * 4 + r)) * 768 + colq + dj * 16 + frow] =
          (__bf16)o[r];
  }
}

// -------- row L2-normalize (512-wide) fp32 (+bias) -> bf16 (for kw) ---------------
__global__ __launch_bounds__(256) void l2norm_bf16_k(const float* __restrict__ src,
                                                     const float* __restrict__ cb,
                                                     __bf16* __restrict__ dst) {
  __shared__ float red[4];
  const int rix = blockIdx.x, tid = threadIdx.x;
  const float* row = src + (size_t)rix * 512;
  const float v0 = row[tid] + cb[tid];
  const float v1 = row[tid + 256] + cb[tid + 256];
  const float tot = blk_sum256(v0 * v0 + v1 * v1, red);
  const float inv = 1.f / fmaxf(sqrtf(tot), 1e-8f);
  dst[(size_t)rix * 512 + tid] = (__bf16)(v0 * inv);
  dst[(size_t)rix * 512 + tid + 256] = (__bf16)(v1 * inv);
}

// -------- final: sum split-K slices, scale by 1/rowsum ----------------------------
__global__ __launch_bounds__(256) void final_reduce_k(const float* __restrict__ slices,
                                                      const float* __restrict__ rs,
                                                      float* __restrict__ out) {
  const int m = blockIdx.x, d = threadIdx.x;
  const float inv = 1.f / rs[m];
  float s0 = 0.f, s1 = 0.f;
#pragma unroll
  for (int z = 0; z < ZSL; ++z) {
    const float* sl = slices + (size_t)z * M_ * TD_ + (size_t)m * TD_;
    s0 += sl[d];
    s1 += sl[d + 256];
  }
  out[(size_t)m * TD_ + d] = s0 * inv;
  out[(size_t)m * TD_ + d + 256] = s1 * inv;
}

extern "C" void kernel_launch(void* const* d_in, const int* in_sizes, int n_in,
                              void* d_out, int out_size, void* d_ws, size_t ws_size,
                              hipStream_t stream) {
  const float* audio = (const float*)d_in[0];
  const float* ln1g = (const float*)d_in[1];
  const float* ln1b = (const float*)d_in[2];
  const float* wq = (const float*)d_in[3];
  const float* bq = (const float*)d_in[4];
  const float* wk = (const float*)d_in[5];
  const float* bk = (const float*)d_in[6];
  const float* wv = (const float*)d_in[7];
  const float* bv = (const float*)d_in[8];
  const float* wo = (const float*)d_in[9];
  const float* bo = (const float*)d_in[10];
  const float* lnag = (const float*)d_in[11];
  const float* lnab = (const float*)d_in[12];
  const float* w1 = (const float*)d_in[13];
  const float* b1 = (const float*)d_in[14];
  const float* w2 = (const float*)d_in[15];
  const float* b2 = (const float*)d_in[16];
  const float* lnbg = (const float*)d_in[17];
  const float* lnbb = (const float*)d_in[18];
  const float* wp = (const float*)d_in[19];
  const float* bp = (const float*)d_in[20];
  const float* emb = (const float*)d_in[21];
  const int* alen = (const int*)d_in[22];
  const int* align = (const int*)d_in[23];
  const int* anum = (const int*)d_in[24];
  float* out = (float*)d_out;

  char* p = (char*)d_ws;
  auto alloc = [&](size_t bytes) {
    char* r = p;
    p += (bytes + 255) & ~(size_t)255;
    return r;
  };
  // --- overlay: transformer temporaries (dead by vocab stage) double as kwslice ---
  float* kwslice = (float*)d_ws;
  float* srcsum = (float*)alloc((size_t)M_ * 768 * 4);
  float* srcf = (float*)alloc((size_t)M_ * 768 * 4);
  __bf16* srcb = (__bf16*)alloc((size_t)M_ * 768 * 2);
  float* qkv = (float*)alloc((size_t)M_ * 2304 * 4);
  __bf16* ctxb = (__bf16*)alloc((size_t)M_ * 768 * 2);
  float* ybuf = (float*)alloc((size_t)M_ * 768 * 4);
  float* ybuf2 = (float*)alloc((size_t)M_ * 768 * 4);
  float* xf = (float*)alloc((size_t)M_ * 768 * 4);
  __bf16* xb = (__bf16*)alloc((size_t)M_ * 768 * 2);
  float* hf = (float*)alloc((size_t)M_ * FF_ * 4);
  __bf16* hb = (__bf16*)alloc((size_t)M_ * FF_ * 2);
  __bf16* x2b = (__bf16*)alloc((size_t)M_ * 768 * 2);
  float* kw = (float*)alloc((size_t)M_ * 512 * 4);
  {  // pad overlay region to >= kwslice size (ZSL slices of [M_][TD_] fp32)
    const size_t need = (size_t)ZSL * M_ * TD_ * 4;
    const size_t cur = (size_t)(p - (char*)d_ws);
    if (cur < need) alloc(need - cur);
  }
  // --- persistent-through-vocab allocations ---
  __bf16* kwn = (__bf16*)alloc((size_t)M_ * 512 * 2);
  float* rs = (float*)alloc((size_t)M_ * 4);
  __bf16* wqkvT = (__bf16*)alloc((size_t)2304 * 768 * 2);
  __bf16* woT = (__bf16*)alloc((size_t)768 * 768 * 2);
  __bf16* w1T = (__bf16*)alloc((size_t)3072 * 768 * 2);
  __bf16* w2T = (__bf16*)alloc((size_t)768 * 3072 * 2);
  __bf16* wpT = (__bf16*)alloc((size_t)512 * 768 * 2);
  float* bqkv = (float*)alloc((size_t)2304 * 4);

  const size_t used = (size_t)(p - (char*)d_ws);
  const size_t avail = (ws_size > used + 4096) ? (ws_size - used - 4096) : 0;
  const size_t perTile = ((size_t)128 * 512 * 2) * 2 + (size_t)1024 * 128 * 2;
  size_t tp = avail / perTile;
  if (tp < 1) tp = 1;
  if (tp > 386) tp = 386;
  const int tilesPer = (int)tp;
  const int nChunks = (386 + tilesPer - 1) / tilesPer;
  const int maxCols = tilesPer * 128;
  __bf16* embnC = (__bf16*)alloc((size_t)maxCols * 512 * 2);
  __bf16* embTC = (__bf16*)alloc((size_t)512 * maxCols * 2);
  __bf16* Ec = (__bf16*)alloc((size_t)1024 * maxCols * 2);

  // one batched zero for srcsum/qkv/ybuf/ybuf2/kw/hf/rs (replaces 5-6 memsets)
  zero6_k<<<2048, 256, 0, stream>>>((float4*)srcsum, (float4*)qkv, (float4*)ybuf,
                                    (float4*)ybuf2, (float4*)kw, (float4*)hf,
                                    (float4*)rs);
  if (nChunks > 1) hipMemsetAsync(kwslice, 0, (size_t)ZSL * M_ * TD_ * 4, stream);

  // weight prep (single launch)
  prep_all_k<<<7305, 256, 0, stream>>>(wq, wk, wv, wo, w1, w2, wp, bq, bk, bv,
                                       wqkvT, woT, w1T, w2T, wpT, bqkv);

  // pooling + transformer (split-K MODE 6, z in {2,4}: measured optimum R12)
  seg_partial_k<<<dim3(16, T_ / SCH), 256, 0, stream>>>(audio, align, alen, srcsum);
  pool_fin_k<<<M_, 256, 0, stream>>>(srcsum, align, alen, anum, ln1g, ln1b, srcf, srcb);
  gemm_nt<6, 0><<<dim3(8, 18, 2), 256, 0, stream>>>(srcb, wqkvT, nullptr, qkv, 2304, 768, 12);
  attn_k<<<128, 256, 0, stream>>>(qkv, bqkv, anum, ctxb);
  gemm_nt<6, 0><<<dim3(8, 6, 2), 256, 0, stream>>>(ctxb, woT, nullptr, ybuf, 768, 768, 12);
  add_ln_k<<<M_, 256, 0, stream>>>(ybuf, srcf, bo, lnag, lnab, xf, xb);
  gemm_nt<6, 0><<<dim3(8, 24, 2), 256, 0, stream>>>(xb, w1T, nullptr, hf, 3072, 768, 12);
  relu_bf16_k<<<3072, 256, 0, stream>>>(hf, b1, hb);
  gemm_nt<6, 0><<<dim3(8, 6, 4), 256, 0, stream>>>(hb, w2T, nullptr, ybuf2, 768, 3072, 24);
  add_ln_k<<<M_, 256, 0, stream>>>(ybuf2, xf, b2, lnbg, lnbb, nullptr, x2b);
  gemm_nt<6, 0><<<dim3(8, 4, 4), 256, 0, stream>>>(x2b, wpT, nullptr, kw, 512, 768, 6);
  l2norm_bf16_k<<<M_, 256, 0, stream>>>(kw, bp, kwn);

  // vocab stage (overlay region dead from here -> kwslice live)
  if (nChunks == 1) {
    embprep_k<<<V_ / 32, 256, 0, stream>>>(emb, embnC, embTC, V_);
    gemm_big_exp<<<4 * 386, 256, 0, stream>>>(kwn, embnC, Ec, rs, V_, 512, 386);
    const int kpz = (V_ / 32 + ZSL - 1) / ZSL;  // 49
    gemm_nt<4, 2><<<1024, 256, 0, stream>>>(Ec, embTC, nullptr, kwslice, 512, V_, kpz);
  } else {
    for (int c = 0; c < nChunks; ++c) {
      const int t0 = c * tilesPer;
      const int nt = min(tilesPer, 386 - t0);
      const int v0 = t0 * 128, nc = nt * 128;
      embprep_k<<<nc / 32, 256, 0, stream>>>(emb + (size_t)v0 * 512, embnC, embTC, nc);
      gemm_big_exp<<<4 * nt, 256, 0, stream>>>(kwn, embnC, Ec, rs, nc, 512, nt);
      const int totIt = nc >> 5;
      const int kpz = (totIt + ZSL - 1) / ZSL;
      gemm_nt<5, 0><<<dim3(8, 4, ZSL), 256, 0, stream>>>(Ec, embTC, nullptr, kwslice, 512, nc, kpz);
    }
  }
  final_reduce_k<<<M_, 256, 0, stream>>>(kwslice, rs, out);
}